// Round 11
// baseline (1818.759 us; speedup 1.0000x reference)
//
#include <hip/hip_runtime.h>

#define Hc 96
#define Wc 96
#define Cc 256
#define Bc 4
#define KK 9
#define HW 9216          // Hc*Wc
#define PIX 36864        // Bc*HW
#define CK 2304          // Cc*KK

typedef _Float16 f16;
typedef __attribute__((ext_vector_type(4))) _Float16 f16x4;
typedef __attribute__((ext_vector_type(8))) _Float16 f16x8;
typedef __attribute__((ext_vector_type(4))) float f32x4;

__device__ __forceinline__ int clampi(int v, int lo, int hi) {
    return v < lo ? lo : (v > hi ? hi : v);
}

#define SB() __builtin_amdgcn_sched_barrier(0)

// ---------- prep: NCHW fp32 -> NHWC f16 (layer 0 input) ----------
__global__ __launch_bounds__(256) void nhwc_prep_kernel(
    const float* __restrict__ x0, f16* __restrict__ x16)
{
    __shared__ float st[64][65];
    const int hw0 = blockIdx.x * 64;
    const int c0  = blockIdx.y * 64;
    const int b   = blockIdx.z;
    const int tid = threadIdx.x;
    const int a = tid & 63, r = tid >> 6;
#pragma unroll
    for (int it = 0; it < 16; ++it) {
        int cl = it * 4 + r;
        st[cl][a] = x0[((size_t)(b * Cc + c0 + cl)) * HW + hw0 + a];
    }
    __syncthreads();
#pragma unroll
    for (int it = 0; it < 16; ++it) {
        int hwl = it * 4 + r;
        x16[((size_t)(b * HW + hw0 + hwl)) * Cc + c0 + a] = (f16)st[a][hwl];
    }
}

// wT2[(k*256 + o)*256 + c] = (f16) w[(o*256 + c)*9 + k]
__global__ __launch_bounds__(256) void transpose_w_kernel(
    const float* __restrict__ w, f16* __restrict__ wT2)
{
    int u = blockIdx.x * 256 + threadIdx.x;   // < 589824
    int c = u & 255, o = (u >> 8) & 255, k = u >> 16;
    wT2[u] = (f16)w[(o * Cc + c) * KK + k];
}

// woffT[(k*32 + j)*256 + c] = (f16) w_off[(j*256 + c)*9 + k], rows 18..31 = 0
__global__ __launch_bounds__(256) void woff_prep_kernel(
    const float* __restrict__ w_off, f16* __restrict__ woffT)
{
    int u = blockIdx.x * 256 + threadIdx.x;   // < 73728
    int c = u & 255, j = (u >> 8) & 31, k = u >> 13;
    float v = (j < 18) ? w_off[((size_t)j * Cc + c) * KK + k] : 0.f;
    woffT[u] = (f16)v;
}

// bilinear decomposition for one tap -> idx4/wt4 (tap-major layout)
__device__ __forceinline__ void store_tap(int k, int h, int w, float offy, float offx,
    int p, int4* __restrict__ idx4t, float4* __restrict__ wt4t)
{
    float py = (float)(h - 1 + k / 3) + offy;
    float px = (float)(w - 1 + k % 3) + offx;
    float y0f = floorf(py), x0f = floorf(px);
    float wy = py - y0f, wx = px - x0f;
    int iy0 = (int)y0f, ix0 = (int)x0f;
    float vy0 = (y0f >= 0.f && y0f <= 95.f) ? 1.f : 0.f;
    float vy1 = (y0f + 1.f >= 0.f && y0f + 1.f <= 95.f) ? 1.f : 0.f;
    float vx0 = (x0f >= 0.f && x0f <= 95.f) ? 1.f : 0.f;
    float vx1 = (x0f + 1.f >= 0.f && x0f + 1.f <= 95.f) ? 1.f : 0.f;
    int cy0 = clampi(iy0, 0, 95), cy1 = clampi(iy0 + 1, 0, 95);
    int cx0 = clampi(ix0, 0, 95), cx1 = clampi(ix0 + 1, 0, 95);
    idx4t[(size_t)k * PIX + p] = make_int4(cy0 * Wc + cx0, cy0 * Wc + cx1,
                                           cy1 * Wc + cx0, cy1 * Wc + cx1);
    wt4t[(size_t)k * PIX + p] = make_float4((1.f - wy) * (1.f - wx) * vy0 * vx0,
                                            (1.f - wy) * wx * vy0 * vx1,
                                            wy * (1.f - wx) * vy1 * vx0,
                                            wy * wx * vy1 * vx1);
}

// Offset conv as f16 MFMA GEMM, reg-staged double-buffered pipeline.
// Block: 256 threads (4 waves = 2M x 2N), tile 32 out x 64 pixels. 576 blocks.
__global__ __launch_bounds__(256) void conv_off_mfma_kernel(
    const f16* __restrict__ x16, const f16* __restrict__ woffT,
    const float* __restrict__ b_off,
    int4* __restrict__ idx4t, float4* __restrict__ wt4t)
{
    __shared__ __align__(16) f16 s_a[2][32 * 32];   // 2 x 2KB
    __shared__ __align__(16) f16 s_b[2][64 * 32];   // 2 x 4KB
    const int bid = blockIdx.x;
    const int swz = (bid & 7) * 72 + (bid >> 3);    // 576 blocks, XCD-chunked
    const int p0 = swz * 64;
    const int imgb = (p0 / HW) * HW;
    const int tid = threadIdx.x, lane = tid & 63, wid = tid >> 6;
    const int wm = wid >> 1, wn = wid & 1;
    const int qa = ((lane >> 4) ^ ((lane >> 1) & 3)) * 8;
    // A-stage mapping: row/col-quad
    const int arow = tid >> 3, acb = tid & 7;
    const int adst = arow * 32 + (((acb >> 1) ^ ((arow >> 1) & 3)) * 8) + (acb & 1) * 4;
    // B-stage mapping: 4 lanes per pixel (coalesced 64B), pixel ps, group cg
    const int ps = tid >> 2, cg = tid & 3;
    const int bdst = ps * 32 + ((cg ^ ((ps >> 1) & 3)) * 8);
    const int hwp = p0 + ps - imgb;
    const int hp = hwp / Wc, wp = hwp - hp * Wc;

#define CLOAD(q, aD, bD) do {                                                  \
    int p2_ = (q) > 71 ? 71 : (q);                                             \
    int k2_ = p2_ >> 3, c2_ = p2_ & 7;                                         \
    int ky_ = k2_ / 3, kx_ = k2_ - ky_ * 3;                                    \
    int yy_ = hp + ky_ - 1, xx_ = wp + kx_ - 1;                                \
    bool v_ = (yy_ >= 0 && yy_ < Hc && xx_ >= 0 && xx_ < Wc);                  \
    aD = *(const f16x4*)(woffT + ((size_t)(k2_ * 32 + arow)) * Cc + c2_ * 32 + acb * 4); \
    f16x8 t_ = {0, 0, 0, 0, 0, 0, 0, 0};                                       \
    if (v_) t_ = *(const f16x8*)(x16 + ((size_t)(imgb + yy_ * Wc + xx_)) * Cc + c2_ * 32 + cg * 8); \
    bD = t_;                                                                   \
} while (0)

    f32x4 acc[2];
    acc[0] = (f32x4){0.f, 0.f, 0.f, 0.f};
    acc[1] = (f32x4){0.f, 0.f, 0.f, 0.f};

    f16x4 aR0, aR1;
    f16x8 bR0, bR1;
    // prologue: phase 0 -> slot0 -> s[0]; phase 1 -> slot1 (held in regs)
    CLOAD(0, aR0, bR0);
    CLOAD(1, aR1, bR1);
    *(f16x4*)&s_a[0][adst] = aR0;
    *(f16x8*)&s_b[0][bdst] = bR0;
    asm volatile("s_waitcnt lgkmcnt(0)" ::: "memory"); SB();
    __builtin_amdgcn_s_barrier(); SB();

#define CBODY(p, aCur, bCur, aNxt, bNxt, bc, bn) do {                          \
    f16x8 af = *(const f16x8*)&s_a[bc][(wm * 16 + (lane & 15)) * 32 + qa];     \
    f16x8 bf0 = *(const f16x8*)&s_b[bc][(wn * 32 + (lane & 15)) * 32 + qa];    \
    f16x8 bf1 = *(const f16x8*)&s_b[bc][(wn * 32 + 16 + (lane & 15)) * 32 + qa];\
    CLOAD((p) + 2, aCur, bCur);                                                \
    acc[0] = __builtin_amdgcn_mfma_f32_16x16x32_f16(af, bf0, acc[0], 0, 0, 0); \
    acc[1] = __builtin_amdgcn_mfma_f32_16x16x32_f16(af, bf1, acc[1], 0, 0, 0); \
    *(f16x4*)&s_a[bn][adst] = aNxt;                                            \
    *(f16x8*)&s_b[bn][bdst] = bNxt;                                            \
    asm volatile("s_waitcnt lgkmcnt(0)" ::: "memory"); SB();                   \
    __builtin_amdgcn_s_barrier(); SB();                                        \
} while (0)

    for (int p = 0; p < 72; p += 2) {
        CBODY(p,     aR0, bR0, aR1, bR1, 0, 1);
        CBODY(p + 1, aR1, bR1, aR0, bR0, 1, 0);
    }

    // epilogue: wm=0 -> taps 0..7 (rows 4g..4g+3), wm=1 -> tap 8 (rows 16,17)
    const int g = lane >> 4;
#pragma unroll
    for (int ni = 0; ni < 2; ++ni) {
        const int p = p0 + wn * 32 + ni * 16 + (lane & 15);
        const int hwq = p - imgb;
        const int hq = hwq / Wc, wq = hwq - hq * Wc;
        if (wm == 0) {
            store_tap(2 * g,     hq, wq, acc[ni][0] + b_off[4 * g],
                                         acc[ni][1] + b_off[4 * g + 1], p, idx4t, wt4t);
            store_tap(2 * g + 1, hq, wq, acc[ni][2] + b_off[4 * g + 2],
                                         acc[ni][3] + b_off[4 * g + 3], p, idx4t, wt4t);
        } else if (g == 0) {
            store_tap(8, hq, wq, acc[ni][0] + b_off[16],
                                 acc[ni][1] + b_off[17], p, idx4t, wt4t);
        }
    }
#undef CLOAD
#undef CBODY
}

// Fused deformable sampling (f16 NHWC gathers) + f16 MFMA GEMM + ReLU.
// Block: 256 threads (4 waves), tile 256 out x 64 pix; wave = 64x64. 576 blocks.
// R7 structure with weight ring reduced 4->2 (LDS 73.7KB -> 40KB = 4 blocks/CU,
// 16 waves/CU). Ring-2 safety: explicit vmcnt(4) at chunk top retires W(t)
// (issued a full chunk earlier; outstanding there = W(t)x4 + C(t+1)x4).
// Blend's compiler-counted vmcnt covers corners as before. No traffic change.
__global__ __launch_bounds__(256, 4) void deform_mfma_kernel(
    const f16* __restrict__ x16, const f16* __restrict__ wT2,
    const int4* __restrict__ idx4t, const float4* __restrict__ wt4t,
    f16* __restrict__ o16, float* __restrict__ oN, int last)
{
    __shared__ __align__(16) f16 s_w[2][8192];  // 2 x 16KB ring [o(256)][kk(32)] swz
    __shared__ __align__(16) f16 s_s[2][2048];  // 2 x 4KB [pix(64)][kk(32)] swz

    const int bid = blockIdx.x;
    const int swz = (bid & 7) * 72 + (bid >> 3); // 576 blocks, XCD-chunked
    const int p0 = swz * 64;
    const int imgb = (p0 / HW) * HW;
    const int tid = threadIdx.x, lane = tid & 63, wid = tid >> 6;
    const int ps = tid >> 2, cg = tid & 3;       // sampling: pixel ps, 8-ch grp cg
    const int qa = ((lane >> 4) ^ ((lane >> 1) & 3)) * 8;
    const int qs = (cg ^ ((ps >> 1) & 3)) * 8;
    const f16* xb = x16 + (size_t)imgb * Cc;

#define ISSUE_W(kt, cw, nb) do {                                               \
    _Pragma("unroll")                                                          \
    for (int i_ = 0; i_ < 4; ++i_) {                                           \
        int u_ = i_ * 256 + tid;                                               \
        int wr_ = u_ >> 2;                                                     \
        int wc_ = ((u_ & 3) ^ ((u_ >> 3) & 3)) * 8;                            \
        const f16* g_ = wT2 + ((size_t)((kt) * 256 + wr_)) * Cc + (cw) * 32 + wc_; \
        __builtin_amdgcn_global_load_lds(                                      \
            (const __attribute__((address_space(1))) void*)g_,                 \
            (__attribute__((address_space(3))) void*)&s_w[nb][u_ * 8], 16, 0, 0); \
    }                                                                          \
} while (0)

// 4 lanes (cg=0..3) of pixel ps read contiguous 64B per corner
#define ISSUE_C(dst, idv, co) do {                                             \
    (dst)[0] = *(const f16x8*)(xb + (size_t)(idv).x * Cc + (co) + cg * 8);     \
    (dst)[1] = *(const f16x8*)(xb + (size_t)(idv).y * Cc + (co) + cg * 8);     \
    (dst)[2] = *(const f16x8*)(xb + (size_t)(idv).z * Cc + (co) + cg * 8);     \
    (dst)[3] = *(const f16x8*)(xb + (size_t)(idv).w * Cc + (co) + cg * 8);     \
} while (0)

#define BLEND_WRITE(src, wvv, nb) do {                                         \
    f16x8 sv_;                                                                 \
    _Pragma("unroll")                                                          \
    for (int j_ = 0; j_ < 8; ++j_) {                                           \
        float s_ = (wvv).x * (float)(src)[0][j_] + (wvv).y * (float)(src)[1][j_]\
                 + (wvv).z * (float)(src)[2][j_] + (wvv).w * (float)(src)[3][j_];\
        sv_[j_] = (f16)s_;                                                     \
    }                                                                          \
    *(f16x8*)&s_s[nb][ps * 32 + qs] = sv_;                                     \
} while (0)

    f32x4 acc[4][4];
#pragma unroll
    for (int mi = 0; mi < 4; ++mi)
#pragma unroll
        for (int ni = 0; ni < 4; ++ni) acc[mi][ni] = (f32x4){0.f, 0.f, 0.f, 0.f};

    f16x8 c4[2][4];
    int4 id = idx4t[p0 + ps];
    float4 wv = wt4t[p0 + ps];
    int4 idN;
    float4 wvN;

    // prologue: W(chunk0)->buf0; C(chunk0)->blend->s_s[0]; C(chunk1) in flight.
    // Blend's counted vmcnt retires W(0)+C(0) (in-order), leaving C(1)x4.
    ISSUE_W(0, 0, 0);
    SB();
    ISSUE_C(c4[1], id, 0);                 // corners for chunk 0
    ISSUE_C(c4[0], id, 32);                // corners for chunk 1
    BLEND_WRITE(c4[1], wv, 0);
    asm volatile("s_waitcnt lgkmcnt(0)" ::: "memory"); SB();
    __builtin_amdgcn_s_barrier(); SB();

    for (int k = 0; k < 9; ++k) {
        const int kn = (k < 8) ? k + 1 : 8;
#pragma unroll
        for (int ch = 0; ch < 8; ++ch) {
            const int bb = ch & 1, nb = bb ^ 1;
            // retire W(t) (issued last chunk; older than the in-flight corners)
            asm volatile("s_waitcnt vmcnt(4)" ::: "memory"); SB();
            f16x8 af[4], bf[4];
#pragma unroll
            for (int mi = 0; mi < 4; ++mi)
                af[mi] = *(const f16x8*)&s_w[bb][(wid * 64 + mi * 16 + (lane & 15)) * 32 + qa];
#pragma unroll
            for (int ni = 0; ni < 4; ++ni)
                bf[ni] = *(const f16x8*)&s_s[bb][(ni * 16 + (lane & 15)) * 32 + qa];
            if (ch == 0) {
                idN = idx4t[(size_t)kn * PIX + p0 + ps];
                wvN = wt4t[(size_t)kn * PIX + p0 + ps];
            }
            // weights for chunk t+1 (into the buffer read at t-1), then
            // corners for chunk t+2 (order pinned by SB)
            ISSUE_W((ch == 7) ? kn : k, (ch + 1) & 7, nb);
            SB();
            {
                const int4 idu = (ch >= 6) ? idN : id;
                ISSUE_C(c4[nb], idu, ((ch + 2) & 7) * 32);
            }
            // blend corners for chunk t+1 (issued at t-1; compiler emits
            // counted vmcnt leaving W(t+1)+C(t+2) in flight)
            {
                const float4 wvu = (ch == 7) ? wvN : wv;
                BLEND_WRITE(c4[bb], wvu, nb);
            }
            asm volatile("s_waitcnt lgkmcnt(0)" ::: "memory"); SB();
#pragma unroll
            for (int ni = 0; ni < 4; ++ni)
#pragma unroll
                for (int mi = 0; mi < 4; ++mi)
                    acc[mi][ni] = __builtin_amdgcn_mfma_f32_16x16x32_f16(
                        af[mi], bf[ni], acc[mi][ni], 0, 0, 0);
            __builtin_amdgcn_s_barrier(); SB();
        }
        id = idN;
        wv = wvN;
    }

    // epilogue: ReLU; D row = output = (lane>>4)*4+j, col = pixel = lane&15
    if (!last) {
#pragma unroll
        for (int ni = 0; ni < 4; ++ni) {
            const int p = p0 + ni * 16 + (lane & 15);
#pragma unroll
            for (int mi = 0; mi < 4; ++mi) {
                const int o0 = wid * 64 + mi * 16 + (lane >> 4) * 4;
                f32x4 v = acc[mi][ni];
                f16x4 h = {(f16)fmaxf(v[0], 0.f), (f16)fmaxf(v[1], 0.f),
                           (f16)fmaxf(v[2], 0.f), (f16)fmaxf(v[3], 0.f)};
                *(f16x4*)&o16[(size_t)p * Cc + o0] = h;
            }
        }
    } else {
        const int bimg = imgb / HW;
#pragma unroll
        for (int ni = 0; ni < 4; ++ni) {
            const int p = p0 + ni * 16 + (lane & 15);
            const int hwl = p - imgb;
#pragma unroll
            for (int mi = 0; mi < 4; ++mi) {
                const int o0 = wid * 64 + mi * 16 + (lane >> 4) * 4;
#pragma unroll
                for (int j = 0; j < 4; ++j)
                    oN[((size_t)(bimg * Cc + o0 + j)) * HW + hwl] =
                        fmaxf(acc[mi][ni][j], 0.f);
            }
        }
    }
#undef ISSUE_W
#undef ISSUE_C
#undef BLEND_WRITE
}

extern "C" void kernel_launch(void* const* d_in, const int* in_sizes, int n_in,
                              void* d_out, int out_size, void* d_ws, size_t ws_size,
                              hipStream_t stream)
{
    const float* x0 = (const float*)d_in[0];
    float* out = (float*)d_out;

    f16*   x16a = (f16*)d_ws;                          // PIX*Cc f16
    f16*   x16b = x16a + (size_t)PIX * Cc;             // PIX*Cc f16
    f16*   wT2  = x16b + (size_t)PIX * Cc;             // CK*Cc f16
    f16*   woffT = wT2 + (size_t)CK * Cc;              // 9*32*256 f16
    int4*  idx4t = (int4*)(woffT + (size_t)9 * 32 * Cc);
    float4* wt4t = (float4*)(idx4t + (size_t)KK * PIX);

    nhwc_prep_kernel<<<dim3(HW / 64, Cc / 64, Bc), 256, 0, stream>>>(x0, x16a);

    const f16* xin = x16a;
    for (int L = 0; L < 3; ++L) {
        const float* w_off = (const float*)d_in[1 + 3 * L];
        const float* b_off = (const float*)d_in[2 + 3 * L];
        const float* w     = (const float*)d_in[3 + 3 * L];
        const int last = (L == 2);
        f16* xo = (L == 0) ? x16b : x16a;

        transpose_w_kernel<<<(CK * Cc) / 256, 256, 0, stream>>>(w, wT2);
        woff_prep_kernel<<<(9 * 32 * Cc) / 256, 256, 0, stream>>>(w_off, woffT);
        conv_off_mfma_kernel<<<PIX / 64, 256, 0, stream>>>(xin, woffT, b_off, idx4t, wt4t);
        deform_mfma_kernel<<<PIX / 64, 256, 0, stream>>>(
            xin, wT2, idx4t, wt4t, xo, out, last);

        xin = xo;
    }
}

// Round 13
// 485.625 us; speedup vs baseline: 3.7452x; 3.7452x over previous
//
#include <hip/hip_runtime.h>

#define Hc 96
#define Wc 96
#define Cc 256
#define Bc 4
#define KK 9
#define HW 9216          // Hc*Wc
#define PIX 36864        // Bc*HW
#define CK 2304          // Cc*KK

typedef _Float16 f16;
typedef __attribute__((ext_vector_type(4))) _Float16 f16x4;
typedef __attribute__((ext_vector_type(8))) _Float16 f16x8;
typedef __attribute__((ext_vector_type(4))) float f32x4;

__device__ __forceinline__ int clampi(int v, int lo, int hi) {
    return v < lo ? lo : (v > hi ? hi : v);
}

#define SB() __builtin_amdgcn_sched_barrier(0)

// ---------- prep: NCHW fp32 -> NHWC f16 (layer 0 input) ----------
__global__ __launch_bounds__(256) void nhwc_prep_kernel(
    const float* __restrict__ x0, f16* __restrict__ x16)
{
    __shared__ float st[64][65];
    const int hw0 = blockIdx.x * 64;
    const int c0  = blockIdx.y * 64;
    const int b   = blockIdx.z;
    const int tid = threadIdx.x;
    const int a = tid & 63, r = tid >> 6;
#pragma unroll
    for (int it = 0; it < 16; ++it) {
        int cl = it * 4 + r;
        st[cl][a] = x0[((size_t)(b * Cc + c0 + cl)) * HW + hw0 + a];
    }
    __syncthreads();
#pragma unroll
    for (int it = 0; it < 16; ++it) {
        int hwl = it * 4 + r;
        x16[((size_t)(b * HW + hw0 + hwl)) * Cc + c0 + a] = (f16)st[a][hwl];
    }
}

// wT2[(k*256 + o)*256 + c] = (f16) w[(o*256 + c)*9 + k]
__global__ __launch_bounds__(256) void transpose_w_kernel(
    const float* __restrict__ w, f16* __restrict__ wT2)
{
    int u = blockIdx.x * 256 + threadIdx.x;   // < 589824
    int c = u & 255, o = (u >> 8) & 255, k = u >> 16;
    wT2[u] = (f16)w[(o * Cc + c) * KK + k];
}

// woffT[(k*32 + j)*256 + c] = (f16) w_off[(j*256 + c)*9 + k], rows 18..31 = 0
__global__ __launch_bounds__(256) void woff_prep_kernel(
    const float* __restrict__ w_off, f16* __restrict__ woffT)
{
    int u = blockIdx.x * 256 + threadIdx.x;   // < 73728
    int c = u & 255, j = (u >> 8) & 31, k = u >> 13;
    float v = (j < 18) ? w_off[((size_t)j * Cc + c) * KK + k] : 0.f;
    woffT[u] = (f16)v;
}

// bilinear decomposition for one tap -> idx4/wt4 (tap-major layout)
__device__ __forceinline__ void store_tap(int k, int h, int w, float offy, float offx,
    int p, int4* __restrict__ idx4t, float4* __restrict__ wt4t)
{
    float py = (float)(h - 1 + k / 3) + offy;
    float px = (float)(w - 1 + k % 3) + offx;
    float y0f = floorf(py), x0f = floorf(px);
    float wy = py - y0f, wx = px - x0f;
    int iy0 = (int)y0f, ix0 = (int)x0f;
    float vy0 = (y0f >= 0.f && y0f <= 95.f) ? 1.f : 0.f;
    float vy1 = (y0f + 1.f >= 0.f && y0f + 1.f <= 95.f) ? 1.f : 0.f;
    float vx0 = (x0f >= 0.f && x0f <= 95.f) ? 1.f : 0.f;
    float vx1 = (x0f + 1.f >= 0.f && x0f + 1.f <= 95.f) ? 1.f : 0.f;
    int cy0 = clampi(iy0, 0, 95), cy1 = clampi(iy0 + 1, 0, 95);
    int cx0 = clampi(ix0, 0, 95), cx1 = clampi(ix0 + 1, 0, 95);
    idx4t[(size_t)k * PIX + p] = make_int4(cy0 * Wc + cx0, cy0 * Wc + cx1,
                                           cy1 * Wc + cx0, cy1 * Wc + cx1);
    wt4t[(size_t)k * PIX + p] = make_float4((1.f - wy) * (1.f - wx) * vy0 * vx0,
                                            (1.f - wy) * wx * vy0 * vx1,
                                            wy * (1.f - wx) * vy1 * vx0,
                                            wy * wx * vy1 * vx1);
}

// Offset conv as f16 MFMA GEMM, reg-staged double-buffered pipeline.
// Block: 256 threads (4 waves = 2M x 2N), tile 32 out x 64 pixels. 576 blocks.
__global__ __launch_bounds__(256) void conv_off_mfma_kernel(
    const f16* __restrict__ x16, const f16* __restrict__ woffT,
    const float* __restrict__ b_off,
    int4* __restrict__ idx4t, float4* __restrict__ wt4t)
{
    __shared__ __align__(16) f16 s_a[2][32 * 32];   // 2 x 2KB
    __shared__ __align__(16) f16 s_b[2][64 * 32];   // 2 x 4KB
    const int bid = blockIdx.x;
    const int swz = (bid & 7) * 72 + (bid >> 3);    // 576 blocks, XCD-chunked
    const int p0 = swz * 64;
    const int imgb = (p0 / HW) * HW;
    const int tid = threadIdx.x, lane = tid & 63, wid = tid >> 6;
    const int wm = wid >> 1, wn = wid & 1;
    const int qa = ((lane >> 4) ^ ((lane >> 1) & 3)) * 8;
    // A-stage mapping: row/col-quad
    const int arow = tid >> 3, acb = tid & 7;
    const int adst = arow * 32 + (((acb >> 1) ^ ((arow >> 1) & 3)) * 8) + (acb & 1) * 4;
    // B-stage mapping: 4 lanes per pixel (coalesced 64B), pixel ps, group cg
    const int ps = tid >> 2, cg = tid & 3;
    const int bdst = ps * 32 + ((cg ^ ((ps >> 1) & 3)) * 8);
    const int hwp = p0 + ps - imgb;
    const int hp = hwp / Wc, wp = hwp - hp * Wc;

#define CLOAD(q, aD, bD) do {                                                  \
    int p2_ = (q) > 71 ? 71 : (q);                                             \
    int k2_ = p2_ >> 3, c2_ = p2_ & 7;                                         \
    int ky_ = k2_ / 3, kx_ = k2_ - ky_ * 3;                                    \
    int yy_ = hp + ky_ - 1, xx_ = wp + kx_ - 1;                                \
    bool v_ = (yy_ >= 0 && yy_ < Hc && xx_ >= 0 && xx_ < Wc);                  \
    aD = *(const f16x4*)(woffT + ((size_t)(k2_ * 32 + arow)) * Cc + c2_ * 32 + acb * 4); \
    f16x8 t_ = {0, 0, 0, 0, 0, 0, 0, 0};                                       \
    if (v_) t_ = *(const f16x8*)(x16 + ((size_t)(imgb + yy_ * Wc + xx_)) * Cc + c2_ * 32 + cg * 8); \
    bD = t_;                                                                   \
} while (0)

    f32x4 acc[2];
    acc[0] = (f32x4){0.f, 0.f, 0.f, 0.f};
    acc[1] = (f32x4){0.f, 0.f, 0.f, 0.f};

    f16x4 aR0, aR1;
    f16x8 bR0, bR1;
    // prologue: phase 0 -> slot0 -> s[0]; phase 1 -> slot1 (held in regs)
    CLOAD(0, aR0, bR0);
    CLOAD(1, aR1, bR1);
    *(f16x4*)&s_a[0][adst] = aR0;
    *(f16x8*)&s_b[0][bdst] = bR0;
    asm volatile("s_waitcnt lgkmcnt(0)" ::: "memory"); SB();
    __builtin_amdgcn_s_barrier(); SB();

#define CBODY(p, aCur, bCur, aNxt, bNxt, bc, bn) do {                          \
    f16x8 af = *(const f16x8*)&s_a[bc][(wm * 16 + (lane & 15)) * 32 + qa];     \
    f16x8 bf0 = *(const f16x8*)&s_b[bc][(wn * 32 + (lane & 15)) * 32 + qa];    \
    f16x8 bf1 = *(const f16x8*)&s_b[bc][(wn * 32 + 16 + (lane & 15)) * 32 + qa];\
    CLOAD((p) + 2, aCur, bCur);                                                \
    acc[0] = __builtin_amdgcn_mfma_f32_16x16x32_f16(af, bf0, acc[0], 0, 0, 0); \
    acc[1] = __builtin_amdgcn_mfma_f32_16x16x32_f16(af, bf1, acc[1], 0, 0, 0); \
    *(f16x4*)&s_a[bn][adst] = aNxt;                                            \
    *(f16x8*)&s_b[bn][bdst] = bNxt;                                            \
    asm volatile("s_waitcnt lgkmcnt(0)" ::: "memory"); SB();                   \
    __builtin_amdgcn_s_barrier(); SB();                                        \
} while (0)

    for (int p = 0; p < 72; p += 2) {
        CBODY(p,     aR0, bR0, aR1, bR1, 0, 1);
        CBODY(p + 1, aR1, bR1, aR0, bR0, 1, 0);
    }

    // epilogue: wm=0 -> taps 0..7 (rows 4g..4g+3), wm=1 -> tap 8 (rows 16,17)
    const int g = lane >> 4;
#pragma unroll
    for (int ni = 0; ni < 2; ++ni) {
        const int p = p0 + wn * 32 + ni * 16 + (lane & 15);
        const int hwq = p - imgb;
        const int hq = hwq / Wc, wq = hwq - hq * Wc;
        if (wm == 0) {
            store_tap(2 * g,     hq, wq, acc[ni][0] + b_off[4 * g],
                                         acc[ni][1] + b_off[4 * g + 1], p, idx4t, wt4t);
            store_tap(2 * g + 1, hq, wq, acc[ni][2] + b_off[4 * g + 2],
                                         acc[ni][3] + b_off[4 * g + 3], p, idx4t, wt4t);
        } else if (g == 0) {
            store_tap(8, hq, wq, acc[ni][0] + b_off[16],
                                 acc[ni][1] + b_off[17], p, idx4t, wt4t);
        }
    }
#undef CLOAD
#undef CBODY
}

// Fused deformable sampling (f16 NHWC gathers) + f16 MFMA GEMM + ReLU.
// Block: 256 threads (4 waves), tile 256 out x 64 pix; wave = 64x64. 576 blocks.
// Ring-2 weights (LDS 40KB) with the R6-proven RACE-FREE wait discipline:
// each wave retires its OWN W(t+1) gload_lds writes via vmcnt(4) BEFORE the
// end-of-chunk barrier, so no wave can read s_w[nb] before all writes land.
// (R11/R12's top-of-chunk wait was after the barrier -> cross-wave race.)
// Single corner reg buffer (blend-then-reissue; saves 16 VGPRs) so
// __launch_bounds__(256,3) (170 unified regs) fits without spilling ->
// 3 blocks/CU = 12 waves/CU vs R7's 2 blocks, zero traffic change.
__global__ __launch_bounds__(256, 3) void deform_mfma_kernel(
    const f16* __restrict__ x16, const f16* __restrict__ wT2,
    const int4* __restrict__ idx4t, const float4* __restrict__ wt4t,
    f16* __restrict__ o16, float* __restrict__ oN, int last)
{
    __shared__ __align__(16) f16 s_w[2][8192];  // 2 x 16KB [o(256)][kk(32)] swz
    __shared__ __align__(16) f16 s_s[2][2048];  // 2 x 4KB  [pix(64)][kk(32)] swz

    const int bid = blockIdx.x;
    const int swz = (bid & 7) * 72 + (bid >> 3); // 576 blocks, XCD-chunked
    const int p0 = swz * 64;
    const int imgb = (p0 / HW) * HW;
    const int tid = threadIdx.x, lane = tid & 63, wid = tid >> 6;
    const int ps = tid >> 2, cg = tid & 3;       // sampling: pixel ps, 8-ch grp cg
    const int qa = ((lane >> 4) ^ ((lane >> 1) & 3)) * 8;
    const int qs = (cg ^ ((ps >> 1) & 3)) * 8;
    const f16* xb = x16 + (size_t)imgb * Cc;

#define ISSUE_W(kt, cw, nb) do {                                               \
    _Pragma("unroll")                                                          \
    for (int i_ = 0; i_ < 4; ++i_) {                                           \
        int u_ = i_ * 256 + tid;                                               \
        int wr_ = u_ >> 2;                                                     \
        int wc_ = ((u_ & 3) ^ ((u_ >> 3) & 3)) * 8;                            \
        const f16* g_ = wT2 + ((size_t)((kt) * 256 + wr_)) * Cc + (cw) * 32 + wc_; \
        __builtin_amdgcn_global_load_lds(                                      \
            (const __attribute__((address_space(1))) void*)g_,                 \
            (__attribute__((address_space(3))) void*)&s_w[nb][u_ * 8], 16, 0, 0); \
    }                                                                          \
} while (0)

// 4 lanes (cg=0..3) of pixel ps read contiguous 64B per corner
#define ISSUE_C(dst, idv, co) do {                                             \
    (dst)[0] = *(const f16x8*)(xb + (size_t)(idv).x * Cc + (co) + cg * 8);     \
    (dst)[1] = *(const f16x8*)(xb + (size_t)(idv).y * Cc + (co) + cg * 8);     \
    (dst)[2] = *(const f16x8*)(xb + (size_t)(idv).z * Cc + (co) + cg * 8);     \
    (dst)[3] = *(const f16x8*)(xb + (size_t)(idv).w * Cc + (co) + cg * 8);     \
} while (0)

#define BLEND_WRITE(src, wvv, nb) do {                                         \
    f16x8 sv_;                                                                 \
    _Pragma("unroll")                                                          \
    for (int j_ = 0; j_ < 8; ++j_) {                                           \
        float s_ = (wvv).x * (float)(src)[0][j_] + (wvv).y * (float)(src)[1][j_]\
                 + (wvv).z * (float)(src)[2][j_] + (wvv).w * (float)(src)[3][j_];\
        sv_[j_] = (f16)s_;                                                     \
    }                                                                          \
    *(f16x8*)&s_s[nb][ps * 32 + qs] = sv_;                                     \
} while (0)

    f32x4 acc[4][4];
#pragma unroll
    for (int mi = 0; mi < 4; ++mi)
#pragma unroll
        for (int ni = 0; ni < 4; ++ni) acc[mi][ni] = (f32x4){0.f, 0.f, 0.f, 0.f};

    f16x8 c4[4];                 // single corner buffer (next chunk's corners)
    int4 id = idx4t[p0 + ps];
    float4 wv = wt4t[p0 + ps];
    int4 idN;
    float4 wvN;

    // prologue: W(chunk0)->buf0; C(0)->blend->s_s[0] (waits C(0), which also
    // retires W(0) in-order); then C(1) into the same regs. Queue at loop
    // entry: C(1)x4 — the steady-state invariant.
    ISSUE_W(0, 0, 0);
    SB();
    ISSUE_C(c4, id, 0);                    // corners for chunk 0
    BLEND_WRITE(c4, wv, 0);
    ISSUE_C(c4, id, 32);                   // corners for chunk 1
    asm volatile("s_waitcnt lgkmcnt(0)" ::: "memory"); SB();
    __builtin_amdgcn_s_barrier(); SB();

    for (int k = 0; k < 9; ++k) {
        const int kn = (k < 8) ? k + 1 : 8;
#pragma unroll
        for (int ch = 0; ch < 8; ++ch) {
            const int bb = ch & 1, nb = bb ^ 1;
            f16x8 af[4], bf[4];
#pragma unroll
            for (int mi = 0; mi < 4; ++mi)
                af[mi] = *(const f16x8*)&s_w[bb][(wid * 64 + mi * 16 + (lane & 15)) * 32 + qa];
#pragma unroll
            for (int ni = 0; ni < 4; ++ni)
                bf[ni] = *(const f16x8*)&s_s[bb][(ni * 16 + (lane & 15)) * 32 + qa];
            if (ch == 0) {
                idN = idx4t[(size_t)kn * PIX + p0 + ps];
                wvN = wt4t[(size_t)kn * PIX + p0 + ps];
            }
            // weights for chunk t+1 into the buffer read at t-1
            ISSUE_W((ch == 7) ? kn : k, (ch + 1) & 7, nb);
            SB();
            // blend corners for chunk t+1 (c4, issued last chunk; compiler's
            // counted vmcnt retires C(t+1) and, in-order, any id loads)
            {
                const float4 wvu = (ch == 7) ? wvN : wv;
                BLEND_WRITE(c4, wvu, nb);
            }
            // corners for chunk t+2 into the SAME regs (after blend's reads)
            {
                const int4 idu = (ch >= 6) ? idN : id;
                ISSUE_C(c4, idu, ((ch + 2) & 7) * 32);
            }
            asm volatile("s_waitcnt lgkmcnt(0)" ::: "memory"); SB();
#pragma unroll
            for (int ni = 0; ni < 4; ++ni)
#pragma unroll
                for (int mi = 0; mi < 4; ++mi)
                    acc[mi][ni] = __builtin_amdgcn_mfma_f32_16x16x32_f16(
                        af[mi], bf[ni], acc[mi][ni], 0, 0, 0);
            // RACE-FREE POINT: retire this wave's W(t+1) writes (outstanding
            // here = [W(t+1)x4 oldest, C(t+2)x4]) BEFORE the barrier, so all
            // waves' s_w[nb] writes are complete when anyone reads them next.
            asm volatile("s_waitcnt vmcnt(4)" ::: "memory"); SB();
            __builtin_amdgcn_s_barrier(); SB();
        }
        id = idN;
        wv = wvN;
    }

    // epilogue: ReLU; D row = output = (lane>>4)*4+j, col = pixel = lane&15
    if (!last) {
#pragma unroll
        for (int ni = 0; ni < 4; ++ni) {
            const int p = p0 + ni * 16 + (lane & 15);
#pragma unroll
            for (int mi = 0; mi < 4; ++mi) {
                const int o0 = wid * 64 + mi * 16 + (lane >> 4) * 4;
                f32x4 v = acc[mi][ni];
                f16x4 h = {(f16)fmaxf(v[0], 0.f), (f16)fmaxf(v[1], 0.f),
                           (f16)fmaxf(v[2], 0.f), (f16)fmaxf(v[3], 0.f)};
                *(f16x4*)&o16[(size_t)p * Cc + o0] = h;
            }
        }
    } else {
        const int bimg = imgb / HW;
#pragma unroll
        for (int ni = 0; ni < 4; ++ni) {
            const int p = p0 + ni * 16 + (lane & 15);
            const int hwl = p - imgb;
#pragma unroll
            for (int mi = 0; mi < 4; ++mi) {
                const int o0 = wid * 64 + mi * 16 + (lane >> 4) * 4;
#pragma unroll
                for (int j = 0; j < 4; ++j)
                    oN[((size_t)(bimg * Cc + o0 + j)) * HW + hwl] =
                        fmaxf(acc[mi][ni][j], 0.f);
            }
        }
    }
#undef ISSUE_W
#undef ISSUE_C
#undef BLEND_WRITE
}

extern "C" void kernel_launch(void* const* d_in, const int* in_sizes, int n_in,
                              void* d_out, int out_size, void* d_ws, size_t ws_size,
                              hipStream_t stream)
{
    const float* x0 = (const float*)d_in[0];
    float* out = (float*)d_out;

    f16*   x16a = (f16*)d_ws;                          // PIX*Cc f16
    f16*   x16b = x16a + (size_t)PIX * Cc;             // PIX*Cc f16
    f16*   wT2  = x16b + (size_t)PIX * Cc;             // CK*Cc f16
    f16*   woffT = wT2 + (size_t)CK * Cc;              // 9*32*256 f16
    int4*  idx4t = (int4*)(woffT + (size_t)9 * 32 * Cc);
    float4* wt4t = (float4*)(idx4t + (size_t)KK * PIX);

    nhwc_prep_kernel<<<dim3(HW / 64, Cc / 64, Bc), 256, 0, stream>>>(x0, x16a);

    const f16* xin = x16a;
    for (int L = 0; L < 3; ++L) {
        const float* w_off = (const float*)d_in[1 + 3 * L];
        const float* b_off = (const float*)d_in[2 + 3 * L];
        const float* w     = (const float*)d_in[3 + 3 * L];
        const int last = (L == 2);
        f16* xo = (L == 0) ? x16b : x16a;

        transpose_w_kernel<<<(CK * Cc) / 256, 256, 0, stream>>>(w, wT2);
        woff_prep_kernel<<<(9 * 32 * Cc) / 256, 256, 0, stream>>>(w_off, woffT);
        conv_off_mfma_kernel<<<PIX / 64, 256, 0, stream>>>(xin, woffT, b_off, idx4t, wt4t);
        deform_mfma_kernel<<<PIX / 64, 256, 0, stream>>>(
            xin, wT2, idx4t, wt4t, xo, out, last);

        xin = xo;
    }
}